// Round 8
// baseline (1157.280 us; speedup 1.0000x reference)
//
#include <hip/hip_runtime.h>
#include <float.h>

#define BB 128
#define N1 21
#define N2 4096
#define CC 256   // C (points2 channels)
#define LCH 256  // LC
#define HH 128   // H
#define KNN 64
#define KP 268   // LDS X row stride in f16 (256 + pad; 8B-aligned rows)

typedef _Float16 f16;
typedef f16 f16x4 __attribute__((ext_vector_type(4)));
typedef f16 f16x8 __attribute__((ext_vector_type(8)));
typedef float f32x4 __attribute__((ext_vector_type(4)));

// ---- workspace layout (float units) ----
static const size_t OFF_A1  = 0;                                   // [2688][256] f32
static const size_t OFF_KNN = OFF_A1 + (size_t)BB * N1 * 256;      // [2688][64] int
static const size_t OFF_W4T = OFF_KNN + (size_t)BB * N1 * KNN;     // [256][256] f32
static const size_t OFF_W5T = OFF_W4T + 65536;
static const size_t OFF_P1H = OFF_W5T + 65536;                     // each pack: 65536 f16 = 32768 f32
static const size_t OFF_P1L = OFF_P1H + 32768;
static const size_t OFF_P2H = OFF_P1L + 32768;
static const size_t OFF_P2L = OFF_P2H + 32768;
static const size_t OFF_P3H = OFF_P2L + 32768;
static const size_t OFF_P3L = OFF_P3H + 32768;
static const size_t OFF_P2T = OFF_P3L + 32768;                     // [B][N2][C] u32 (hi|lo f16) = 512 MB

// prep grid partition: 6 consecutive bids = 5 t2-blocks + 1 other-block
#define NT2    32768            // t2 blocks (BB * 256)
#define NOTHER 6656             // 2688 knn + 2688 biasfold + 1280 pack
#define NPREP  (NOTHER * 6)     // 39936

__device__ __forceinline__ float lrelu(float x) { return x > 0.f ? x : 0.1f * x; }
__device__ __forceinline__ f16 f16bits(unsigned short b) { f16 r; __builtin_memcpy(&r, &b, 2); return r; }
__device__ __forceinline__ unsigned short bits16(f16 h) { unsigned short r; __builtin_memcpy(&r, &h, 2); return r; }

// fragment k-mapping kappa(lane,j) = 4*(lane>>4) + (j&3) + 16*(j>>2), used for BOTH
// A and B packing -> k-permutation cancels in the dot product.

__device__ __forceinline__ void pack_one(int e, const float* __restrict__ w, int stride, int koff,
                                         f16* __restrict__ hi, f16* __restrict__ lo) {
  int j = e & 7, lane = (e >> 3) & 63, ntg = (e >> 9) & 15, ks = e >> 13;
  int n = ntg * 16 + (lane & 15);
  int k = ks * 32 + 4 * (lane >> 4) + (j & 3) + 16 * (j >> 2);
  float v = w[(size_t)n * stride + koff + k];
  f16 h = (f16)v;
  f16 l = (f16)(v - (float)h);
  hi[e] = h; lo[e] = l;
}

// ================= k_prep: t2 + knn + biasfold + pack, block-partitioned =================
// All four sub-kernels are mutually independent; fusing them into one launch lets the
// BW-bound t2 blocks overlap the latency/VALU-bound knn/biasfold/pack blocks (same-stream
// separate launches serialize). 5:1 interleave keeps the mix uniform over the dispatch.
__global__ __launch_bounds__(256) void k_prep(
    const float* __restrict__ points2, unsigned int* __restrict__ p2t,
    const float* __restrict__ xyz1, const float* __restrict__ xyz2,
    int* __restrict__ knn,
    const float* __restrict__ points1,
    const float* __restrict__ w1, const float* __restrict__ bb1,
    const float* __restrict__ g1, const float* __restrict__ be1,
    const float* __restrict__ w2, const float* __restrict__ bb2,
    const float* __restrict__ g2, const float* __restrict__ be2,
    const float* __restrict__ w3, const float* __restrict__ bb3,
    const float* __restrict__ g3, const float* __restrict__ be3,
    const float* __restrict__ w1mlp,
    const float* __restrict__ mw1, const float* __restrict__ mw2,
    const float* __restrict__ mw3, const float* __restrict__ mw4,
    const float* __restrict__ mw5,
    float* __restrict__ A1out, float* __restrict__ ws) {
  __shared__ __align__(16) unsigned char smem[16896];
  int bid = blockIdx.x;
  int q = bid / 6, r = bid - q * 6;
  int t = threadIdx.x;

  if (r < 5) {
    // ---------- t2: points2 [B][C][N2] f32 -> P2T [B][N2][C] u32(hi|lo f16) ----------
    int t2i = q * 5 + r;
    if (t2i >= NT2) return;
    unsigned int (*tile)[65] = (unsigned int (*)[65])smem;
    int b = t2i >> 8;
    int rem = t2i & 255;
    int n0 = (rem >> 2) << 6;
    int c0 = (rem & 3) << 6;
    int tl = t & 63, tg = t >> 6;
    const float* src = points2 + ((size_t)b * CC) * N2;
    #pragma unroll
    for (int i = 0; i < 16; i++) {
      int cl = tg * 16 + i;
      float v = src[(size_t)(c0 + cl) * N2 + n0 + tl];
      f16 h = (f16)v;
      f16 l = (f16)(v - (float)h);
      tile[cl][tl] = (unsigned int)bits16(h) | ((unsigned int)bits16(l) << 16);
    }
    __syncthreads();
    unsigned int* dst = p2t + ((size_t)b * N2) * CC;
    #pragma unroll
    for (int i = 0; i < 16; i++) {
      int nl = tg * 16 + i;
      dst[(size_t)(n0 + nl) * CC + c0 + tl] = tile[tl][nl];
    }
    return;
  }

  int oid = q;
  if (oid < BB * N1) {
    // ---------- kNN (64 smallest of 4096) ----------
    float* dist = (float*)smem;                 // 4096 f32
    float* wvv  = dist + N2;                    // 4
    int*   wii  = (int*)(wvv + 4);              // 4
    int blk = oid;
    int b = blk / N1, n = blk % N1;
    float ax = xyz1[((size_t)b * 3 + 0) * N1 + n];
    float ay = xyz1[((size_t)b * 3 + 1) * N1 + n];
    float az = xyz1[((size_t)b * 3 + 2) * N1 + n];
    float xx1 = ax * ax + ay * ay + az * az;
    const float* X = xyz2 + (size_t)b * 3 * N2;
    for (int i = 0; i < 16; i++) {
      int j = t + i * 256;
      float px = X[j], py = X[N2 + j], pz = X[2 * N2 + j];
      float xx2 = px * px + py * py + pz * pz;
      float dot = ax * px + ay * py + az * pz;
      dist[j] = (xx1 + xx2) - 2.0f * dot;
    }
    __syncthreads();
    int* out = knn + (size_t)blk * KNN;
    for (int it = 0; it < KNN; it++) {
      float best = FLT_MAX;
      int bi = N2;
      for (int i = 0; i < 16; i++) {
        int j = t + i * 256;
        float v = dist[j];
        if (v < best) { best = v; bi = j; }
      }
      for (int off = 32; off; off >>= 1) {
        float ov = __shfl_down(best, off);
        int oi = __shfl_down(bi, off);
        if (ov < best || (ov == best && oi < bi)) { best = ov; bi = oi; }
      }
      int w = t >> 6;
      if ((t & 63) == 0) { wvv[w] = best; wii[w] = bi; }
      __syncthreads();
      if (t == 0) {
        float bv = wvv[0]; int bj = wii[0];
        for (int p = 1; p < 4; p++)
          if (wvv[p] < bv || (wvv[p] == bv && wii[p] < bj)) { bv = wvv[p]; bj = wii[p]; }
        out[it] = bj;
        dist[bj] = FLT_MAX;
      }
      __syncthreads();
    }
    return;
  }
  oid -= BB * N1;
  if (oid < BB * N1) {
    // ---------- biasfold -> A1 (p1-part of mlp layer 1 folded in) ----------
    float* x0  = (float*)smem;        // 256
    float* x1s = x0 + 256;            // 128
    float* x2s = x1s + 128;
    float* x3s = x2s + 128;
    int blk = oid;
    int b = blk / N1, n = blk % N1;
    const float bnS = 1.0f / sqrtf(1.0f + 1e-5f);
    if (t < 128) {
      x0[t]       = points1[((size_t)b * LCH + t) * N1 + n];
      x0[t + 128] = points1[((size_t)b * LCH + t + 128) * N1 + n];
    }
    __syncthreads();
    if (t < 128) {
      float acc = 0.f;
      const float* wr = w1 + (size_t)t * LCH;
      #pragma unroll 4
      for (int c = 0; c < LCH; c++) acc += wr[c] * x0[c];
      acc += bb1[t * N1 + n];
      acc = acc * (g1[t] * bnS) + be1[t];
      x1s[t] = lrelu(acc);
    }
    __syncthreads();
    if (t < 128) {
      float acc = 0.f;
      const float* wr = w2 + (size_t)t * HH;
      #pragma unroll 4
      for (int c = 0; c < HH; c++) acc += wr[c] * x1s[c];
      acc += bb2[t * N1 + n];
      acc = acc * (g2[t] * bnS) + be2[t];
      x2s[t] = lrelu(acc);
    }
    __syncthreads();
    if (t < 128) {
      float acc = 0.f;
      const float* wr = w3 + (size_t)t * HH;
      #pragma unroll 4
      for (int c = 0; c < HH; c++) acc += wr[c] * x2s[c];
      acc += bb3[t * N1 + n];
      acc = acc * (g3[t] * bnS) + be3[t];
      x3s[t] = lrelu(acc);
    }
    __syncthreads();
    {
      const float* wr = w1mlp + (size_t)t * 387;
      float acc = 0.f;
      #pragma unroll 4
      for (int c = 0; c < HH; c++) acc += wr[c] * x3s[c];
      A1out[(size_t)blk * 256 + t] = acc;
    }
    return;
  }
  oid -= BB * N1;
  {
    // ---------- weight pack/split (1280 blocks) ----------
    int e = oid * 256 + t;
    if (e < 131072) {
      int m = e >> 16, v = e & 65535;
      int c = v >> 8, o = v & 255;
      const float* src = m ? mw5 : mw4;
      float* dst = ws + (m ? OFF_W5T : OFF_W4T);
      dst[v] = src[o * 256 + c];
      return;
    }
    int u = e - 131072;
    if (u < 65536) { pack_one(u, mw1, 387, 128, (f16*)(ws + OFF_P1H), (f16*)(ws + OFF_P1L)); return; }
    u -= 65536;
    if (u < 65536) { pack_one(u, mw2, 256, 0, (f16*)(ws + OFF_P2H), (f16*)(ws + OFF_P2L)); return; }
    u -= 65536;
    if (u < 65536) { pack_one(u, mw3, 256, 0, (f16*)(ws + OFF_P3H), (f16*)(ws + OFF_P3L)); return; }
  }
}

// ---------------- MFMA layer: M=64 x N=64 per wave, split-fp16, K=256 ----------------
// ks loop MUST stay rolled (#pragma unroll 1): full unroll hoists all 8 k-steps' B loads
// -> >256 live VGPRs -> scratch spill (r3/r4/r5: 2.25/2.13/1.24 GB WRITE_SIZE).
// M=64: 48 MFMAs per 8 B-loads per iteration (2x the M=32 ratio) hides L2 latency;
// single pass halves weight re-reads and barrier count vs the 2-pass M=32 version.
__device__ __forceinline__ void run_layer64(
    const f16* __restrict__ BH, const f16* __restrict__ BL,
    const f16* Xh, const f16* Xl,
    int w, int lane, int r16, int g, f32x4 acc[4][4]) {
  #pragma unroll 1
  for (int ks = 0; ks < 8; ks++) {
    f16x8 Bh[4], Bl[4];
    #pragma unroll
    for (int nt = 0; nt < 4; nt++) {
      size_t fi = ((size_t)((ks * 16 + w * 4 + nt) * 64 + lane)) * 8;
      Bh[nt] = *(const f16x8*)(BH + fi);
      Bl[nt] = *(const f16x8*)(BL + fi);
    }
    int k0 = ks * 32 + 4 * g;
    f16x8 Ah[4], Al[4];
    #pragma unroll
    for (int mt = 0; mt < 4; mt++) {
      int base = (mt * 16 + r16) * KP + k0;
      f16x4 h0 = *(const f16x4*)(Xh + base);
      f16x4 h1 = *(const f16x4*)(Xh + base + 16);
      f16x4 l0 = *(const f16x4*)(Xl + base);
      f16x4 l1 = *(const f16x4*)(Xl + base + 16);
      Ah[mt] = __builtin_shufflevector(h0, h1, 0, 1, 2, 3, 4, 5, 6, 7);
      Al[mt] = __builtin_shufflevector(l0, l1, 0, 1, 2, 3, 4, 5, 6, 7);
    }
    #pragma unroll
    for (int mt = 0; mt < 4; mt++)
      #pragma unroll
      for (int nt = 0; nt < 4; nt++) {
        acc[mt][nt] = __builtin_amdgcn_mfma_f32_16x16x32_f16(Ah[mt], Bh[nt], acc[mt][nt], 0, 0, 0);
        acc[mt][nt] = __builtin_amdgcn_mfma_f32_16x16x32_f16(Ah[mt], Bl[nt], acc[mt][nt], 0, 0, 0);
        acc[mt][nt] = __builtin_amdgcn_mfma_f32_16x16x32_f16(Al[mt], Bh[nt], acc[mt][nt], 0, 0, 0);
      }
  }
}

__device__ __forceinline__ void writeback_act64(
    f32x4 acc[4][4], const float* __restrict__ bias,
    f16* Xh, f16* Xl, int w, int r16, int g) {
  #pragma unroll
  for (int nt = 0; nt < 4; nt++) {
    int nl = w * 64 + nt * 16 + r16;
    float bv = bias[nl];
    #pragma unroll
    for (int mt = 0; mt < 4; mt++)
      #pragma unroll
      for (int j = 0; j < 4; j++) {
        int m = mt * 16 + 4 * g + j;
        float y = lrelu(acc[mt][nt][j] + bv);
        f16 h = (f16)y;
        Xh[m * KP + nl] = h;
        Xl[m * KP + nl] = (f16)(y - (float)h);
      }
  }
}

// ---------------- k_fused8: gather + MFMA MLP (M=64 single pass) + maxpool + mlp2 + regress ----------------
template <int TRANS>
__global__ __launch_bounds__(256) void k_fused8(
    const float* __restrict__ xyz1, const float* __restrict__ xyz2,
    const float* __restrict__ points2, const unsigned int* __restrict__ p2t,
    const float* __restrict__ A1ws, const int* __restrict__ knn,
    const float* __restrict__ w1mlp,
    const f16* __restrict__ P1H, const f16* __restrict__ P1L,
    const f16* __restrict__ P2H, const f16* __restrict__ P2L,
    const f16* __restrict__ P3H, const f16* __restrict__ P3L,
    const float* __restrict__ b1, const float* __restrict__ b2,
    const float* __restrict__ b3,
    const float* __restrict__ W4T, const float* __restrict__ W5T,
    const float* __restrict__ regw, const float* __restrict__ regb,
    float* __restrict__ out) {
  int bid = blockIdx.x;
  // XCD swizzle: all 21 n1-blocks of a batch land on one XCD (2688 = 8*336)
  int xcd = bid & 7, slot = bid >> 3;
  int b = xcd * 16 + slot / 21;
  int n1 = slot % 21;
  int row = b * N1 + n1;

  int t = threadIdx.x;
  int lane = t & 63, w = t >> 6;
  int r16 = lane & 15, g = lane >> 4;

  __shared__ __align__(16) f16 Xhi[64 * KP];
  __shared__ __align__(16) f16 Xlo[64 * KP];
  __shared__ float dirs[64][3];
  __shared__ int idxs[KNN];
  __shared__ float x1p[3];

  if (t < KNN) idxs[t] = knn[(size_t)row * KNN + t];
  if (t < 3) x1p[t] = xyz1[((size_t)b * 3 + t) * N1 + n1];
  __syncthreads();

  // per-lane constants: A1 + dir-part weights for this lane's 4 output columns
  float a1v[4], wd0[4], wd1[4], wd2[4];
  #pragma unroll
  for (int nt = 0; nt < 4; nt++) {
    int n = w * 64 + nt * 16 + r16;
    a1v[nt] = A1ws[(size_t)row * 256 + n];
    wd0[nt] = w1mlp[(size_t)n * 387 + 384];
    wd1[nt] = w1mlp[(size_t)n * 387 + 385];
    wd2[nt] = w1mlp[(size_t)n * 387 + 386];
  }

  const float* x2b = xyz2 + (size_t)b * 3 * N2;
  // dirs for all 64 neighbors
  if (t < 64) {
    int id = idxs[t];
    #pragma unroll
    for (int d = 0; d < 3; d++)
      dirs[t][d] = x2b[(size_t)d * N2 + id] - x1p[d];
  }
  // gather g2 [64 rows][256 ch]: 4 threads/row, 16 coalesced uint4 each
  if (TRANS) {
    int r = t >> 2, qq = t & 3;
    int id = idxs[r];
    const uint4* src = (const uint4*)(p2t + ((size_t)b * N2 + id) * CC + qq * 64);
    #pragma unroll
    for (int i = 0; i < 16; i++) {
      uint4 v = src[i];
      unsigned int a4[4] = {v.x, v.y, v.z, v.w};
      f16x4 hv, lv;
      #pragma unroll
      for (int j = 0; j < 4; j++) {
        hv[j] = f16bits((unsigned short)(a4[j] & 0xffffu));
        lv[j] = f16bits((unsigned short)(a4[j] >> 16));
      }
      int cpos = r * KP + qq * 64 + i * 4;
      *(f16x4*)(Xhi + cpos) = hv;
      *(f16x4*)(Xlo + cpos) = lv;
    }
  } else {
    int r = t >> 2, qq = t & 3;
    int id = idxs[r];
    const float* src = points2 + (size_t)b * CC * N2 + id;
    #pragma unroll 4
    for (int i = 0; i < 64; i++) {
      int c = qq * 64 + i;
      float v = src[(size_t)c * N2];
      f16 h = (f16)v;
      Xhi[r * KP + c] = h;
      Xlo[r * KP + c] = (f16)(v - (float)h);
    }
  }
  __syncthreads();

  f32x4 acc[4][4];
  // ---- layer 1 (K=256 over g2), acc init = A1[n] + W1[n][384:387]·dir[m] ----
  #pragma unroll
  for (int mt = 0; mt < 4; mt++)
    #pragma unroll
    for (int nt = 0; nt < 4; nt++)
      #pragma unroll
      for (int j = 0; j < 4; j++) {
        int m = mt * 16 + 4 * g + j;
        acc[mt][nt][j] = a1v[nt] + wd0[nt] * dirs[m][0]
                                 + wd1[nt] * dirs[m][1]
                                 + wd2[nt] * dirs[m][2];
      }
  run_layer64(P1H, P1L, Xhi, Xlo, w, lane, r16, g, acc);
  __syncthreads();
  writeback_act64(acc, b1, Xhi, Xlo, w, r16, g);
  __syncthreads();

  // ---- layer 2 ----
  #pragma unroll
  for (int mt = 0; mt < 4; mt++)
    #pragma unroll
    for (int nt = 0; nt < 4; nt++) acc[mt][nt] = (f32x4){0.f, 0.f, 0.f, 0.f};
  run_layer64(P2H, P2L, Xhi, Xlo, w, lane, r16, g, acc);
  __syncthreads();
  writeback_act64(acc, b2, Xhi, Xlo, w, r16, g);
  __syncthreads();

  // ---- layer 3 + maxpool over all 64 rows (bias/lrelu deferred; commute with max) ----
  #pragma unroll
  for (int mt = 0; mt < 4; mt++)
    #pragma unroll
    for (int nt = 0; nt < 4; nt++) acc[mt][nt] = (f32x4){0.f, 0.f, 0.f, 0.f};
  run_layer64(P3H, P3L, Xhi, Xlo, w, lane, r16, g, acc);

  float poolm[4];
  #pragma unroll
  for (int nt = 0; nt < 4; nt++) {
    float m = -FLT_MAX;
    #pragma unroll
    for (int mt = 0; mt < 4; mt++)
      #pragma unroll
      for (int j = 0; j < 4; j++) m = fmaxf(m, acc[mt][nt][j]);
    m = fmaxf(m, __shfl_xor(m, 16));
    m = fmaxf(m, __shfl_xor(m, 32));
    poolm[nt] = m;
  }
  __syncthreads();   // all waves done reading X -> reuse as float buffer

  // ---- tail: pooled -> mlp2 -> regress (fp32) ----
  float* fb = (float*)Xhi;   // [0:256) pooled, [256:512) z1, [512:768) z2
  if (g == 0) {
    #pragma unroll
    for (int nt = 0; nt < 4; nt++) {
      int n = w * 64 + nt * 16 + r16;
      fb[n] = lrelu(poolm[nt] + b3[n]);
    }
  }
  __syncthreads();
  {
    float a = 0.f;
    #pragma unroll 4
    for (int c = 0; c < 256; c++) a += W4T[(size_t)c * 256 + t] * fb[c];
    fb[256 + t] = lrelu(a);
  }
  __syncthreads();
  {
    float a = 0.f;
    #pragma unroll 4
    for (int c = 0; c < 256; c++) a += W5T[(size_t)c * 256 + t] * fb[256 + c];
    fb[512 + t] = lrelu(a);
  }
  __syncthreads();
  if (t < 192) {
    int o = t >> 6;
    float a = 0.f;
    #pragma unroll
    for (int i = 0; i < 4; i++) {
      int c = (t & 63) + 64 * i;
      a += regw[o * 256 + c] * fb[512 + c];
    }
    #pragma unroll
    for (int off = 32; off; off >>= 1) a += __shfl_xor(a, off);
    if ((t & 63) == 0) out[((size_t)b * 3 + o) * N1 + n1] = a + regb[o];
  }
}

extern "C" void kernel_launch(void* const* d_in, const int* in_sizes, int n_in,
                              void* d_out, int out_size, void* d_ws, size_t ws_size,
                              hipStream_t stream) {
  const float* xyz1    = (const float*)d_in[0];
  const float* xyz2    = (const float*)d_in[1];
  const float* points1 = (const float*)d_in[2];
  const float* points2 = (const float*)d_in[3];
  const float* bf_w1 = (const float*)d_in[4],  *bf_b1 = (const float*)d_in[5];
  const float* bf_g1 = (const float*)d_in[6],  *bf_e1 = (const float*)d_in[7];
  const float* bf_w2 = (const float*)d_in[8],  *bf_b2 = (const float*)d_in[9];
  const float* bf_g2 = (const float*)d_in[10], *bf_e2 = (const float*)d_in[11];
  const float* bf_w3 = (const float*)d_in[12], *bf_b3 = (const float*)d_in[13];
  const float* bf_g3 = (const float*)d_in[14], *bf_e3 = (const float*)d_in[15];
  const float* mlp_w1 = (const float*)d_in[16], *mlp_b1 = (const float*)d_in[17];
  const float* mlp_w2 = (const float*)d_in[18], *mlp_b2 = (const float*)d_in[19];
  const float* mlp_w3 = (const float*)d_in[20], *mlp_b3 = (const float*)d_in[21];
  const float* mlp2_w1 = (const float*)d_in[22], *mlp2_w2 = (const float*)d_in[23];
  const float* reg_w = (const float*)d_in[24], *reg_b = (const float*)d_in[25];

  float* ws  = (float*)d_ws;
  float* A1  = ws + OFF_A1;
  int*   knn = (int*)(ws + OFF_KNN);
  unsigned int* p2t = (unsigned int*)(ws + OFF_P2T);

  float* out = (float*)d_out;
  int rows = BB * N1;  // 2688

  size_t need_bytes = (OFF_P2T + (size_t)BB * N2 * CC) * sizeof(float);
  bool use_trans = (ws_size >= need_bytes);

  k_prep<<<NPREP, 256, 0, stream>>>(
      points2, p2t, xyz1, xyz2, knn, points1,
      bf_w1, bf_b1, bf_g1, bf_e1,
      bf_w2, bf_b2, bf_g2, bf_e2,
      bf_w3, bf_b3, bf_g3, bf_e3,
      mlp_w1, mlp_w1, mlp_w2, mlp_w3, mlp2_w1, mlp2_w2, A1, ws);

  if (use_trans)
    k_fused8<1><<<rows, 256, 0, stream>>>(xyz1, xyz2, points2, p2t, A1, knn, mlp_w1,
        (const f16*)(ws + OFF_P1H), (const f16*)(ws + OFF_P1L),
        (const f16*)(ws + OFF_P2H), (const f16*)(ws + OFF_P2L),
        (const f16*)(ws + OFF_P3H), (const f16*)(ws + OFF_P3L),
        mlp_b1, mlp_b2, mlp_b3,
        ws + OFF_W4T, ws + OFF_W5T, reg_w, reg_b, out);
  else
    k_fused8<0><<<rows, 256, 0, stream>>>(xyz1, xyz2, points2, p2t, A1, knn, mlp_w1,
        (const f16*)(ws + OFF_P1H), (const f16*)(ws + OFF_P1L),
        (const f16*)(ws + OFF_P2H), (const f16*)(ws + OFF_P2L),
        (const f16*)(ws + OFF_P3H), (const f16*)(ws + OFF_P3L),
        mlp_b1, mlp_b2, mlp_b3,
        ws + OFF_W4T, ws + OFF_W5T, reg_w, reg_b, out);
}

// Round 9
// 862.825 us; speedup vs baseline: 1.3413x; 1.3413x over previous
//
#include <hip/hip_runtime.h>
#include <float.h>

#define BB 128
#define N1 21
#define N2 4096
#define CC 256   // C (points2 channels)
#define LCH 256  // LC
#define HH 128   // H
#define KNN 64
#define KP 268   // LDS X row stride in f16 (256 + pad; 8B-aligned rows)

typedef _Float16 f16;
typedef f16 f16x4 __attribute__((ext_vector_type(4)));
typedef f16 f16x8 __attribute__((ext_vector_type(8)));
typedef float f32x4 __attribute__((ext_vector_type(4)));

// ---- workspace layout (float units) ----
static const size_t OFF_A1  = 0;                                   // [2688][256] f32
static const size_t OFF_KNN = OFF_A1 + (size_t)BB * N1 * 256;      // [2688][64] int
static const size_t OFF_W4T = OFF_KNN + (size_t)BB * N1 * KNN;     // [256][256] f32
static const size_t OFF_W5T = OFF_W4T + 65536;
static const size_t OFF_P1H = OFF_W5T + 65536;                     // each pack: 65536 f16 = 32768 f32
static const size_t OFF_P1L = OFF_P1H + 32768;
static const size_t OFF_P2H = OFF_P1L + 32768;
static const size_t OFF_P2L = OFF_P2H + 32768;
static const size_t OFF_P3H = OFF_P2L + 32768;
static const size_t OFF_P3L = OFF_P3H + 32768;
static const size_t OFF_P2T = OFF_P3L + 32768;                     // [B][N2][C] u32 (hi|lo f16) = 512 MB

__device__ __forceinline__ float lrelu(float x) { return x > 0.f ? x : 0.1f * x; }
__device__ __forceinline__ f16 f16bits(unsigned short b) { f16 r; __builtin_memcpy(&r, &b, 2); return r; }
__device__ __forceinline__ unsigned short bits16(f16 h) { unsigned short r; __builtin_memcpy(&r, &h, 2); return r; }

// fragment k-mapping kappa(lane,j) = 4*(lane>>4) + (j&3) + 16*(j>>2), used for BOTH
// A and B packing -> k-permutation cancels in the dot product.

// ---------------- kernel 0: weight pack/split ----------------
__device__ __forceinline__ void pack_one(int e, const float* __restrict__ w, int stride, int koff,
                                         f16* __restrict__ hi, f16* __restrict__ lo) {
  int j = e & 7, lane = (e >> 3) & 63, ntg = (e >> 9) & 15, ks = e >> 13;
  int n = ntg * 16 + (lane & 15);
  int k = ks * 32 + 4 * (lane >> 4) + (j & 3) + 16 * (j >> 2);
  float v = w[(size_t)n * stride + koff + k];
  f16 h = (f16)v;
  f16 l = (f16)(v - (float)h);
  hi[e] = h; lo[e] = l;
}

__global__ __launch_bounds__(256) void k_pack(
    const float* __restrict__ w1, const float* __restrict__ w2,
    const float* __restrict__ w3, const float* __restrict__ w4,
    const float* __restrict__ w5, float* __restrict__ ws) {
  int t = blockIdx.x * 256 + threadIdx.x;
  if (t < 131072) {   // W4T / W5T fp32 transpose
    int m = t >> 16, v = t & 65535;
    int c = v >> 8, o = v & 255;
    const float* src = m ? w5 : w4;
    float* dst = ws + (m ? OFF_W5T : OFF_W4T);
    dst[v] = src[o * 256 + c];
    return;
  }
  int u = t - 131072;
  if (u < 65536) { pack_one(u, w1, 387, 128, (f16*)(ws + OFF_P1H), (f16*)(ws + OFF_P1L)); return; }
  u -= 65536;
  if (u < 65536) { pack_one(u, w2, 256, 0, (f16*)(ws + OFF_P2H), (f16*)(ws + OFF_P2L)); return; }
  u -= 65536;
  if (u < 65536) { pack_one(u, w3, 256, 0, (f16*)(ws + OFF_P3H), (f16*)(ws + OFF_P3L)); return; }
}

// ---------------- kernel 0b: points2 [B][C][N2] f32 -> P2T [B][N2][C] u32(hi|lo f16) ----------------
// Load/store phases explicitly batched into register arrays so 16 global loads stay in
// flight (r8 lesson: 24-VGPR codegen serialized this loop -> 2x slower).
__global__ __launch_bounds__(256) void k_t2(
    const float* __restrict__ points2, unsigned int* __restrict__ p2t) {
  __shared__ unsigned int tile[64][65];
  int bid = blockIdx.x;
  int b = bid >> 8;
  int rem = bid & 255;
  int n0 = (rem >> 2) << 6;   // 64 n2-block
  int c0 = (rem & 3) << 6;    // 64 c-block
  int t = threadIdx.x;
  int tl = t & 63, tg = t >> 6;   // lane-in-64, group 0..3

  const float* src = points2 + ((size_t)b * CC) * N2;
  float v[16];
  #pragma unroll
  for (int i = 0; i < 16; i++)
    v[i] = src[(size_t)(c0 + tg * 16 + i) * N2 + n0 + tl];   // 16 loads in flight
  #pragma unroll
  for (int i = 0; i < 16; i++) {
    f16 h = (f16)v[i];
    f16 l = (f16)(v[i] - (float)h);
    tile[tg * 16 + i][tl] = (unsigned int)bits16(h) | ((unsigned int)bits16(l) << 16);
  }
  __syncthreads();
  unsigned int* dst = p2t + ((size_t)b * N2) * CC;
  unsigned int o[16];
  #pragma unroll
  for (int i = 0; i < 16; i++) o[i] = tile[tl][tg * 16 + i];
  #pragma unroll
  for (int i = 0; i < 16; i++)
    dst[(size_t)(n0 + tg * 16 + i) * CC + c0 + tl] = o[i];
}

// ---------------- kernel 1: biasfold -> A1 (p1-part of mlp layer 1 folded in) ----------------
__global__ __launch_bounds__(128) void k_biasfold(
    const float* __restrict__ points1,
    const float* __restrict__ w1, const float* __restrict__ bb1,
    const float* __restrict__ g1, const float* __restrict__ be1,
    const float* __restrict__ w2, const float* __restrict__ bb2,
    const float* __restrict__ g2, const float* __restrict__ be2,
    const float* __restrict__ w3, const float* __restrict__ bb3,
    const float* __restrict__ g3, const float* __restrict__ be3,
    const float* __restrict__ w1mlp,
    float* __restrict__ A1out) {
  int blk = blockIdx.x;
  int b = blk / N1, n = blk % N1;
  int t = threadIdx.x;
  __shared__ float x0[LCH], x1s[HH], x2s[HH], x3s[HH];
  const float bnS = 1.0f / sqrtf(1.0f + 1e-5f);

  x0[t]       = points1[((size_t)b * LCH + t) * N1 + n];
  x0[t + 128] = points1[((size_t)b * LCH + t + 128) * N1 + n];
  __syncthreads();
  {
    float acc = 0.f;
    const float* wr = w1 + (size_t)t * LCH;
    #pragma unroll 4
    for (int c = 0; c < LCH; c++) acc += wr[c] * x0[c];
    acc += bb1[t * N1 + n];
    acc = acc * (g1[t] * bnS) + be1[t];
    x1s[t] = lrelu(acc);
  }
  __syncthreads();
  {
    float acc = 0.f;
    const float* wr = w2 + (size_t)t * HH;
    #pragma unroll 4
    for (int c = 0; c < HH; c++) acc += wr[c] * x1s[c];
    acc += bb2[t * N1 + n];
    acc = acc * (g2[t] * bnS) + be2[t];
    x2s[t] = lrelu(acc);
  }
  __syncthreads();
  {
    float acc = 0.f;
    const float* wr = w3 + (size_t)t * HH;
    #pragma unroll 4
    for (int c = 0; c < HH; c++) acc += wr[c] * x2s[c];
    acc += bb3[t * N1 + n];
    acc = acc * (g3[t] * bnS) + be3[t];
    x3s[t] = lrelu(acc);
  }
  __syncthreads();
  #pragma unroll
  for (int rep = 0; rep < 2; rep++) {
    int o = t + rep * 128;
    const float* wr = w1mlp + (size_t)o * 387;
    float acc = 0.f;
    #pragma unroll 4
    for (int c = 0; c < HH; c++) acc += wr[c] * x3s[c];
    A1out[(size_t)blk * 256 + o] = acc;
  }
}

// ---------------- kernel 2: kNN with register-resident distances ----------------
// 16 dists/thread live in VGPRs; each extract = 15 reg min-selects + shuffle reduce
// + 16 cndmask invalidation. No LDS dist array (r8 lesson: LDS scan was the
// dominant LDS-pipe cost: 64 iters x 16 ds_read/thread). LDS ~48 B -> 8 blocks/CU.
__global__ __launch_bounds__(256) void k_knn(
    const float* __restrict__ xyz1, const float* __restrict__ xyz2,
    int* __restrict__ knn) {
  int blk = blockIdx.x;
  int b = blk / N1, n = blk % N1;
  int t = threadIdx.x;
  __shared__ float wvv[4];
  __shared__ int wii[4];

  float ax = xyz1[((size_t)b * 3 + 0) * N1 + n];
  float ay = xyz1[((size_t)b * 3 + 1) * N1 + n];
  float az = xyz1[((size_t)b * 3 + 2) * N1 + n];
  float xx1 = ax * ax + ay * ay + az * az;
  const float* X = xyz2 + (size_t)b * 3 * N2;

  float dl[16];
  #pragma unroll
  for (int i = 0; i < 16; i++) {
    int j = t + i * 256;
    float px = X[j], py = X[N2 + j], pz = X[2 * N2 + j];
    float xx2 = px * px + py * py + pz * pz;
    float dot = ax * px + ay * py + az * pz;
    dl[i] = (xx1 + xx2) - 2.0f * dot;
  }

  int* out = knn + (size_t)blk * KNN;
  for (int it = 0; it < KNN; it++) {
    // per-thread argmin over 16 registers (strict <, ascending i -> lowest j on tie)
    float best = dl[0]; int bs = 0;
    #pragma unroll
    for (int i = 1; i < 16; i++)
      if (dl[i] < best) { best = dl[i]; bs = i; }
    int bi = t + bs * 256;
    // wave reduce with lowest-index tie-break
    #pragma unroll
    for (int off = 32; off; off >>= 1) {
      float ov = __shfl_down(best, off);
      int oi = __shfl_down(bi, off);
      if (ov < best || (ov == best && oi < bi)) { best = ov; bi = oi; }
    }
    int w = t >> 6;
    if ((t & 63) == 0) { wvv[w] = best; wii[w] = bi; }
    __syncthreads();
    // all threads compute the block winner (no thread-0 serialization)
    float bv = wvv[0]; int bj = wii[0];
    #pragma unroll
    for (int p = 1; p < 4; p++)
      if (wvv[p] < bv || (wvv[p] == bv && wii[p] < bj)) { bv = wvv[p]; bj = wii[p]; }
    if (t == 0) out[it] = bj;
    // owning thread invalidates its register copy (static indices only - no scratch)
    if ((bj & 255) == t) {
      int slot = bj >> 8;
      #pragma unroll
      for (int i = 0; i < 16; i++)
        if (i == slot) dl[i] = FLT_MAX;
    }
    __syncthreads();   // wvv/wii reused next iteration
  }
}

// ---------------- MFMA layer: M=64 x N=64 per wave, split-fp16, K=256 ----------------
// ks loop MUST stay rolled (#pragma unroll 1): full unroll hoists all 8 k-steps' B loads
// -> >256 live VGPRs -> scratch spill (r3/r4/r5: 2.25/2.13/1.24 GB WRITE_SIZE).
__device__ __forceinline__ void run_layer64(
    const f16* __restrict__ BH, const f16* __restrict__ BL,
    const f16* Xh, const f16* Xl,
    int w, int lane, int r16, int g, f32x4 acc[4][4]) {
  #pragma unroll 1
  for (int ks = 0; ks < 8; ks++) {
    f16x8 Bh[4], Bl[4];
    #pragma unroll
    for (int nt = 0; nt < 4; nt++) {
      size_t fi = ((size_t)((ks * 16 + w * 4 + nt) * 64 + lane)) * 8;
      Bh[nt] = *(const f16x8*)(BH + fi);
      Bl[nt] = *(const f16x8*)(BL + fi);
    }
    int k0 = ks * 32 + 4 * g;
    f16x8 Ah[4], Al[4];
    #pragma unroll
    for (int mt = 0; mt < 4; mt++) {
      int base = (mt * 16 + r16) * KP + k0;
      f16x4 h0 = *(const f16x4*)(Xh + base);
      f16x4 h1 = *(const f16x4*)(Xh + base + 16);
      f16x4 l0 = *(const f16x4*)(Xl + base);
      f16x4 l1 = *(const f16x4*)(Xl + base + 16);
      Ah[mt] = __builtin_shufflevector(h0, h1, 0, 1, 2, 3, 4, 5, 6, 7);
      Al[mt] = __builtin_shufflevector(l0, l1, 0, 1, 2, 3, 4, 5, 6, 7);
    }
    #pragma unroll
    for (int mt = 0; mt < 4; mt++)
      #pragma unroll
      for (int nt = 0; nt < 4; nt++) {
        acc[mt][nt] = __builtin_amdgcn_mfma_f32_16x16x32_f16(Ah[mt], Bh[nt], acc[mt][nt], 0, 0, 0);
        acc[mt][nt] = __builtin_amdgcn_mfma_f32_16x16x32_f16(Ah[mt], Bl[nt], acc[mt][nt], 0, 0, 0);
        acc[mt][nt] = __builtin_amdgcn_mfma_f32_16x16x32_f16(Al[mt], Bh[nt], acc[mt][nt], 0, 0, 0);
      }
  }
}

__device__ __forceinline__ void writeback_act64(
    f32x4 acc[4][4], const float* __restrict__ bias,
    f16* Xh, f16* Xl, int w, int r16, int g) {
  #pragma unroll
  for (int nt = 0; nt < 4; nt++) {
    int nl = w * 64 + nt * 16 + r16;
    float bv = bias[nl];
    #pragma unroll
    for (int mt = 0; mt < 4; mt++)
      #pragma unroll
      for (int j = 0; j < 4; j++) {
        int m = mt * 16 + 4 * g + j;
        float y = lrelu(acc[mt][nt][j] + bv);
        f16 h = (f16)y;
        Xh[m * KP + nl] = h;
        Xl[m * KP + nl] = (f16)(y - (float)h);
      }
  }
}

// ---------------- k_fused8: gather + MFMA MLP (M=64 single pass) + maxpool + mlp2 + regress ----------------
template <int TRANS>
__global__ __launch_bounds__(256) void k_fused8(
    const float* __restrict__ xyz1, const float* __restrict__ xyz2,
    const float* __restrict__ points2, const unsigned int* __restrict__ p2t,
    const float* __restrict__ A1ws, const int* __restrict__ knn,
    const float* __restrict__ w1mlp,
    const f16* __restrict__ P1H, const f16* __restrict__ P1L,
    const f16* __restrict__ P2H, const f16* __restrict__ P2L,
    const f16* __restrict__ P3H, const f16* __restrict__ P3L,
    const float* __restrict__ b1, const float* __restrict__ b2,
    const float* __restrict__ b3,
    const float* __restrict__ W4T, const float* __restrict__ W5T,
    const float* __restrict__ regw, const float* __restrict__ regb,
    float* __restrict__ out) {
  int bid = blockIdx.x;
  // XCD swizzle: all 21 n1-blocks of a batch land on one XCD (2688 = 8*336)
  int xcd = bid & 7, slot = bid >> 3;
  int b = xcd * 16 + slot / 21;
  int n1 = slot % 21;
  int row = b * N1 + n1;

  int t = threadIdx.x;
  int lane = t & 63, w = t >> 6;
  int r16 = lane & 15, g = lane >> 4;

  __shared__ __align__(16) f16 Xhi[64 * KP];
  __shared__ __align__(16) f16 Xlo[64 * KP];
  __shared__ float dirs[64][3];
  __shared__ int idxs[KNN];
  __shared__ float x1p[3];

  if (t < KNN) idxs[t] = knn[(size_t)row * KNN + t];
  if (t < 3) x1p[t] = xyz1[((size_t)b * 3 + t) * N1 + n1];
  __syncthreads();

  float a1v[4], wd0[4], wd1[4], wd2[4];
  #pragma unroll
  for (int nt = 0; nt < 4; nt++) {
    int n = w * 64 + nt * 16 + r16;
    a1v[nt] = A1ws[(size_t)row * 256 + n];
    wd0[nt] = w1mlp[(size_t)n * 387 + 384];
    wd1[nt] = w1mlp[(size_t)n * 387 + 385];
    wd2[nt] = w1mlp[(size_t)n * 387 + 386];
  }

  const float* x2b = xyz2 + (size_t)b * 3 * N2;
  if (t < 64) {
    int id = idxs[t];
    #pragma unroll
    for (int d = 0; d < 3; d++)
      dirs[t][d] = x2b[(size_t)d * N2 + id] - x1p[d];
  }
  if (TRANS) {
    int r = t >> 2, qq = t & 3;
    int id = idxs[r];
    const uint4* src = (const uint4*)(p2t + ((size_t)b * N2 + id) * CC + qq * 64);
    #pragma unroll
    for (int i = 0; i < 16; i++) {
      uint4 v = src[i];
      unsigned int a4[4] = {v.x, v.y, v.z, v.w};
      f16x4 hv, lv;
      #pragma unroll
      for (int j = 0; j < 4; j++) {
        hv[j] = f16bits((unsigned short)(a4[j] & 0xffffu));
        lv[j] = f16bits((unsigned short)(a4[j] >> 16));
      }
      int cpos = r * KP + qq * 64 + i * 4;
      *(f16x4*)(Xhi + cpos) = hv;
      *(f16x4*)(Xlo + cpos) = lv;
    }
  } else {
    int r = t >> 2, qq = t & 3;
    int id = idxs[r];
    const float* src = points2 + (size_t)b * CC * N2 + id;
    #pragma unroll 4
    for (int i = 0; i < 64; i++) {
      int c = qq * 64 + i;
      float v = src[(size_t)c * N2];
      f16 h = (f16)v;
      Xhi[r * KP + c] = h;
      Xlo[r * KP + c] = (f16)(v - (float)h);
    }
  }
  __syncthreads();

  f32x4 acc[4][4];
  // ---- layer 1 (K=256 over g2), acc init = A1[n] + W1[n][384:387]·dir[m] ----
  #pragma unroll
  for (int mt = 0; mt < 4; mt++)
    #pragma unroll
    for (int nt = 0; nt < 4; nt++)
      #pragma unroll
      for (int j = 0; j < 4; j++) {
        int m = mt * 16 + 4 * g + j;
        acc[mt][nt][j] = a1v[nt] + wd0[nt] * dirs[m][0]
                                 + wd1[nt] * dirs[m][1]
                                 + wd2[nt] * dirs[m][2];
      }
  run_layer64(P1H, P1L, Xhi, Xlo, w, lane, r16, g, acc);
  __syncthreads();
  writeback_act64(acc, b1, Xhi, Xlo, w, r16, g);
  __syncthreads();

  // ---- layer 2 ----
  #pragma unroll
  for (int mt = 0; mt < 4; mt++)
    #pragma unroll
    for (int nt = 0; nt < 4; nt++) acc[mt][nt] = (f32x4){0.f, 0.f, 0.f, 0.f};
  run_layer64(P2H, P2L, Xhi, Xlo, w, lane, r16, g, acc);
  __syncthreads();
  writeback_act64(acc, b2, Xhi, Xlo, w, r16, g);
  __syncthreads();

  // ---- layer 3 + maxpool over all 64 rows (bias/lrelu deferred; commute with max) ----
  #pragma unroll
  for (int mt = 0; mt < 4; mt++)
    #pragma unroll
    for (int nt = 0; nt < 4; nt++) acc[mt][nt] = (f32x4){0.f, 0.f, 0.f, 0.f};
  run_layer64(P3H, P3L, Xhi, Xlo, w, lane, r16, g, acc);

  float poolm[4];
  #pragma unroll
  for (int nt = 0; nt < 4; nt++) {
    float m = -FLT_MAX;
    #pragma unroll
    for (int mt = 0; mt < 4; mt++)
      #pragma unroll
      for (int j = 0; j < 4; j++) m = fmaxf(m, acc[mt][nt][j]);
    m = fmaxf(m, __shfl_xor(m, 16));
    m = fmaxf(m, __shfl_xor(m, 32));
    poolm[nt] = m;
  }
  __syncthreads();   // all waves done reading X -> reuse as float buffer

  // ---- tail: pooled -> mlp2 -> regress (fp32) ----
  float* fb = (float*)Xhi;   // [0:256) pooled, [256:512) z1, [512:768) z2
  if (g == 0) {
    #pragma unroll
    for (int nt = 0; nt < 4; nt++) {
      int n = w * 64 + nt * 16 + r16;
      fb[n] = lrelu(poolm[nt] + b3[n]);
    }
  }
  __syncthreads();
  {
    float a = 0.f;
    #pragma unroll 4
    for (int c = 0; c < 256; c++) a += W4T[(size_t)c * 256 + t] * fb[c];
    fb[256 + t] = lrelu(a);
  }
  __syncthreads();
  {
    float a = 0.f;
    #pragma unroll 4
    for (int c = 0; c < 256; c++) a += W5T[(size_t)c * 256 + t] * fb[256 + c];
    fb[512 + t] = lrelu(a);
  }
  __syncthreads();
  if (t < 192) {
    int o = t >> 6;
    float a = 0.f;
    #pragma unroll
    for (int i = 0; i < 4; i++) {
      int c = (t & 63) + 64 * i;
      a += regw[o * 256 + c] * fb[512 + c];
    }
    #pragma unroll
    for (int off = 32; off; off >>= 1) a += __shfl_xor(a, off);
    if ((t & 63) == 0) out[((size_t)b * 3 + o) * N1 + n1] = a + regb[o];
  }
}

extern "C" void kernel_launch(void* const* d_in, const int* in_sizes, int n_in,
                              void* d_out, int out_size, void* d_ws, size_t ws_size,
                              hipStream_t stream) {
  const float* xyz1    = (const float*)d_in[0];
  const float* xyz2    = (const float*)d_in[1];
  const float* points1 = (const float*)d_in[2];
  const float* points2 = (const float*)d_in[3];
  const float* bf_w1 = (const float*)d_in[4],  *bf_b1 = (const float*)d_in[5];
  const float* bf_g1 = (const float*)d_in[6],  *bf_e1 = (const float*)d_in[7];
  const float* bf_w2 = (const float*)d_in[8],  *bf_b2 = (const float*)d_in[9];
  const float* bf_g2 = (const float*)d_in[10], *bf_e2 = (const float*)d_in[11];
  const float* bf_w3 = (const float*)d_in[12], *bf_b3 = (const float*)d_in[13];
  const float* bf_g3 = (const float*)d_in[14], *bf_e3 = (const float*)d_in[15];
  const float* mlp_w1 = (const float*)d_in[16], *mlp_b1 = (const float*)d_in[17];
  const float* mlp_w2 = (const float*)d_in[18], *mlp_b2 = (const float*)d_in[19];
  const float* mlp_w3 = (const float*)d_in[20], *mlp_b3 = (const float*)d_in[21];
  const float* mlp2_w1 = (const float*)d_in[22], *mlp2_w2 = (const float*)d_in[23];
  const float* reg_w = (const float*)d_in[24], *reg_b = (const float*)d_in[25];

  float* ws  = (float*)d_ws;
  float* A1  = ws + OFF_A1;
  int*   knn = (int*)(ws + OFF_KNN);
  unsigned int* p2t = (unsigned int*)(ws + OFF_P2T);

  float* out = (float*)d_out;
  int rows = BB * N1;  // 2688

  size_t need_bytes = (OFF_P2T + (size_t)BB * N2 * CC) * sizeof(float);
  bool use_trans = (ws_size >= need_bytes);

  k_pack<<<1280, 256, 0, stream>>>(mlp_w1, mlp_w2, mlp_w3, mlp2_w1, mlp2_w2, ws);
  if (use_trans)
    k_t2<<<BB * 256, 256, 0, stream>>>(points2, p2t);
  k_biasfold<<<rows, 128, 0, stream>>>(points1,
      bf_w1, bf_b1, bf_g1, bf_e1,
      bf_w2, bf_b2, bf_g2, bf_e2,
      bf_w3, bf_b3, bf_g3, bf_e3, mlp_w1, A1);
  k_knn<<<rows, 256, 0, stream>>>(xyz1, xyz2, knn);
  if (use_trans)
    k_fused8<1><<<rows, 256, 0, stream>>>(xyz1, xyz2, points2, p2t, A1, knn, mlp_w1,
        (const f16*)(ws + OFF_P1H), (const f16*)(ws + OFF_P1L),
        (const f16*)(ws + OFF_P2H), (const f16*)(ws + OFF_P2L),
        (const f16*)(ws + OFF_P3H), (const f16*)(ws + OFF_P3L),
        mlp_b1, mlp_b2, mlp_b3,
        ws + OFF_W4T, ws + OFF_W5T, reg_w, reg_b, out);
  else
    k_fused8<0><<<rows, 256, 0, stream>>>(xyz1, xyz2, points2, p2t, A1, knn, mlp_w1,
        (const f16*)(ws + OFF_P1H), (const f16*)(ws + OFF_P1L),
        (const f16*)(ws + OFF_P2H), (const f16*)(ws + OFF_P2L),
        (const f16*)(ws + OFF_P3H), (const f16*)(ws + OFF_P3L),
        mlp_b1, mlp_b2, mlp_b3,
        ws + OFF_W4T, ws + OFF_W5T, reg_w, reg_b, out);
}

// Round 10
// 689.644 us; speedup vs baseline: 1.6781x; 1.2511x over previous
//
#include <hip/hip_runtime.h>
#include <float.h>

#define BB 128
#define N1 21
#define N2 4096
#define CC 256   // C (points2 channels)
#define LCH 256  // LC
#define HH 128   // H
#define KNN 64
#define KP 268   // LDS X row stride in f16 (256 + pad; 8B-aligned rows, bank stride 6)

typedef _Float16 f16;
typedef f16 f16x4 __attribute__((ext_vector_type(4)));
typedef f16 f16x8 __attribute__((ext_vector_type(8)));
typedef float f32x4 __attribute__((ext_vector_type(4)));

// ---- workspace layout (float units) ----
static const size_t OFF_A1  = 0;                                   // [2688][256] f32
static const size_t OFF_KNN = OFF_A1 + (size_t)BB * N1 * 256;      // [2688][64] int
static const size_t OFF_W4T = OFF_KNN + (size_t)BB * N1 * KNN;     // [256][256] f32
static const size_t OFF_W5T = OFF_W4T + 65536;
static const size_t OFF_P1H = OFF_W5T + 65536;                     // each pack: 65536 f16 = 32768 f32
static const size_t OFF_P2H = OFF_P1H + 32768;
static const size_t OFF_P3H = OFF_P2H + 32768;
static const size_t OFF_P2T = OFF_P3H + 32768;                     // [B][N2][C] u16 (f16 hi) = 256 MB

__device__ __forceinline__ float lrelu(float x) { return x > 0.f ? x : 0.1f * x; }
__device__ __forceinline__ unsigned short bits16(f16 h) { unsigned short r; __builtin_memcpy(&r, &h, 2); return r; }

// fragment k-mapping kappa(lane,j) = 4*(lane>>4) + (j&3) + 16*(j>>2), used for BOTH
// A and B packing -> k-permutation cancels in the dot product.
// Precision: single-f16 operands (no hi/lo split). Error budget: weights ~0.05,
// activations O(1) -> per-layer rounding sigma ~3e-4, total absmax ~1.5-3e-3,
// vs 6.17e-3 threshold (r9 measured 9.77e-4 with split; margin spent for 3x fewer
// MFMAs, half LDS (4 blocks/CU), half B/gather traffic).

// ---------------- kernel 0: weight pack (f16 hi only) ----------------
__device__ __forceinline__ void pack_one(int e, const float* __restrict__ w, int stride, int koff,
                                         f16* __restrict__ hi) {
  int j = e & 7, lane = (e >> 3) & 63, ntg = (e >> 9) & 15, ks = e >> 13;
  int n = ntg * 16 + (lane & 15);
  int k = ks * 32 + 4 * (lane >> 4) + (j & 3) + 16 * (j >> 2);
  hi[e] = (f16)w[(size_t)n * stride + koff + k];
}

__global__ __launch_bounds__(256) void k_pack(
    const float* __restrict__ w1, const float* __restrict__ w2,
    const float* __restrict__ w3, const float* __restrict__ w4,
    const float* __restrict__ w5, float* __restrict__ ws) {
  int t = blockIdx.x * 256 + threadIdx.x;
  if (t < 131072) {   // W4T / W5T fp32 transpose
    int m = t >> 16, v = t & 65535;
    int c = v >> 8, o = v & 255;
    const float* src = m ? w5 : w4;
    float* dst = ws + (m ? OFF_W5T : OFF_W4T);
    dst[v] = src[o * 256 + c];
    return;
  }
  int u = t - 131072;
  if (u < 65536) { pack_one(u, w1, 387, 128, (f16*)(ws + OFF_P1H)); return; }
  u -= 65536;
  if (u < 65536) { pack_one(u, w2, 256, 0, (f16*)(ws + OFF_P2H)); return; }
  u -= 65536;
  if (u < 65536) { pack_one(u, w3, 256, 0, (f16*)(ws + OFF_P3H)); return; }
}

// ---------------- kernel 0b: points2 [B][C][N2] f32 -> P2T [B][N2][C] u16 (f16) ----------------
// Register-batched phases (r8 lesson: interleaved codegen serialized at 24 VGPR).
__global__ __launch_bounds__(256) void k_t2(
    const float* __restrict__ points2, unsigned short* __restrict__ p2t) {
  __shared__ unsigned short tile[64][66];   // 132B row = 33 banks -> 2-way (free) column reads
  int bid = blockIdx.x;
  int b = bid >> 8;
  int rem = bid & 255;
  int n0 = (rem >> 2) << 6;   // 64 n2-block
  int c0 = (rem & 3) << 6;    // 64 c-block
  int t = threadIdx.x;
  int tl = t & 63, tg = t >> 6;

  const float* src = points2 + ((size_t)b * CC) * N2;
  float v[16];
  #pragma unroll
  for (int i = 0; i < 16; i++)
    v[i] = src[(size_t)(c0 + tg * 16 + i) * N2 + n0 + tl];   // 16 loads in flight
  #pragma unroll
  for (int i = 0; i < 16; i++)
    tile[tg * 16 + i][tl] = bits16((f16)v[i]);
  __syncthreads();
  unsigned short* dst = p2t + ((size_t)b * N2) * CC;
  unsigned short o[16];
  #pragma unroll
  for (int i = 0; i < 16; i++) o[i] = tile[tl][tg * 16 + i];
  #pragma unroll
  for (int i = 0; i < 16; i++)
    dst[(size_t)(n0 + tg * 16 + i) * CC + c0 + tl] = o[i];
}

// ---------------- kernel 1: biasfold -> A1 (p1-part of mlp layer 1 folded in) ----------------
__global__ __launch_bounds__(128) void k_biasfold(
    const float* __restrict__ points1,
    const float* __restrict__ w1, const float* __restrict__ bb1,
    const float* __restrict__ g1, const float* __restrict__ be1,
    const float* __restrict__ w2, const float* __restrict__ bb2,
    const float* __restrict__ g2, const float* __restrict__ be2,
    const float* __restrict__ w3, const float* __restrict__ bb3,
    const float* __restrict__ g3, const float* __restrict__ be3,
    const float* __restrict__ w1mlp,
    float* __restrict__ A1out) {
  int blk = blockIdx.x;
  int b = blk / N1, n = blk % N1;
  int t = threadIdx.x;
  __shared__ float x0[LCH], x1s[HH], x2s[HH], x3s[HH];
  const float bnS = 1.0f / sqrtf(1.0f + 1e-5f);

  x0[t]       = points1[((size_t)b * LCH + t) * N1 + n];
  x0[t + 128] = points1[((size_t)b * LCH + t + 128) * N1 + n];
  __syncthreads();
  {
    float acc = 0.f;
    const float* wr = w1 + (size_t)t * LCH;
    #pragma unroll 4
    for (int c = 0; c < LCH; c++) acc += wr[c] * x0[c];
    acc += bb1[t * N1 + n];
    acc = acc * (g1[t] * bnS) + be1[t];
    x1s[t] = lrelu(acc);
  }
  __syncthreads();
  {
    float acc = 0.f;
    const float* wr = w2 + (size_t)t * HH;
    #pragma unroll 4
    for (int c = 0; c < HH; c++) acc += wr[c] * x1s[c];
    acc += bb2[t * N1 + n];
    acc = acc * (g2[t] * bnS) + be2[t];
    x2s[t] = lrelu(acc);
  }
  __syncthreads();
  {
    float acc = 0.f;
    const float* wr = w3 + (size_t)t * HH;
    #pragma unroll 4
    for (int c = 0; c < HH; c++) acc += wr[c] * x2s[c];
    acc += bb3[t * N1 + n];
    acc = acc * (g3[t] * bnS) + be3[t];
    x3s[t] = lrelu(acc);
  }
  __syncthreads();
  #pragma unroll
  for (int rep = 0; rep < 2; rep++) {
    int o = t + rep * 128;
    const float* wr = w1mlp + (size_t)o * 387;
    float acc = 0.f;
    #pragma unroll 4
    for (int c = 0; c < HH; c++) acc += wr[c] * x3s[c];
    A1out[(size_t)blk * 256 + o] = acc;
  }
}

// ---------------- kernel 2: kNN with register-resident distances (r9, working) ----------------
__global__ __launch_bounds__(256) void k_knn(
    const float* __restrict__ xyz1, const float* __restrict__ xyz2,
    int* __restrict__ knn) {
  int blk = blockIdx.x;
  int b = blk / N1, n = blk % N1;
  int t = threadIdx.x;
  __shared__ float wvv[4];
  __shared__ int wii[4];

  float ax = xyz1[((size_t)b * 3 + 0) * N1 + n];
  float ay = xyz1[((size_t)b * 3 + 1) * N1 + n];
  float az = xyz1[((size_t)b * 3 + 2) * N1 + n];
  float xx1 = ax * ax + ay * ay + az * az;
  const float* X = xyz2 + (size_t)b * 3 * N2;

  float dl[16];
  #pragma unroll
  for (int i = 0; i < 16; i++) {
    int j = t + i * 256;
    float px = X[j], py = X[N2 + j], pz = X[2 * N2 + j];
    float xx2 = px * px + py * py + pz * pz;
    float dot = ax * px + ay * py + az * pz;
    dl[i] = (xx1 + xx2) - 2.0f * dot;
  }

  int* out = knn + (size_t)blk * KNN;
  for (int it = 0; it < KNN; it++) {
    float best = dl[0]; int bs = 0;
    #pragma unroll
    for (int i = 1; i < 16; i++)
      if (dl[i] < best) { best = dl[i]; bs = i; }
    int bi = t + bs * 256;
    #pragma unroll
    for (int off = 32; off; off >>= 1) {
      float ov = __shfl_down(best, off);
      int oi = __shfl_down(bi, off);
      if (ov < best || (ov == best && oi < bi)) { best = ov; bi = oi; }
    }
    int w = t >> 6;
    if ((t & 63) == 0) { wvv[w] = best; wii[w] = bi; }
    __syncthreads();
    float bv = wvv[0]; int bj = wii[0];
    #pragma unroll
    for (int p = 1; p < 4; p++)
      if (wvv[p] < bv || (wvv[p] == bv && wii[p] < bj)) { bv = wvv[p]; bj = wii[p]; }
    if (t == 0) out[it] = bj;
    if ((bj & 255) == t) {
      int slot = bj >> 8;
      #pragma unroll
      for (int i = 0; i < 16; i++)
        if (i == slot) dl[i] = FLT_MAX;
    }
    __syncthreads();
  }
}

// ---------------- MFMA layer: M=64 x N=64 per wave, single f16, K=256 ----------------
// ks loop MUST stay rolled (#pragma unroll 1): full unroll hoists all k-steps' B loads
// -> >256 live VGPRs -> scratch spill (r3/r4/r5: 2.25/2.13/1.24 GB WRITE_SIZE).
__device__ __forceinline__ void run_layer64(
    const f16* __restrict__ BH, const f16* Xh,
    int w, int lane, int r16, int g, f32x4 acc[4][4]) {
  #pragma unroll 1
  for (int ks = 0; ks < 8; ks++) {
    f16x8 Bh[4];
    #pragma unroll
    for (int nt = 0; nt < 4; nt++) {
      size_t fi = ((size_t)((ks * 16 + w * 4 + nt) * 64 + lane)) * 8;
      Bh[nt] = *(const f16x8*)(BH + fi);
    }
    int k0 = ks * 32 + 4 * g;
    f16x8 Ah[4];
    #pragma unroll
    for (int mt = 0; mt < 4; mt++) {
      int base = (mt * 16 + r16) * KP + k0;
      f16x4 h0 = *(const f16x4*)(Xh + base);
      f16x4 h1 = *(const f16x4*)(Xh + base + 16);
      Ah[mt] = __builtin_shufflevector(h0, h1, 0, 1, 2, 3, 4, 5, 6, 7);
    }
    #pragma unroll
    for (int mt = 0; mt < 4; mt++)
      #pragma unroll
      for (int nt = 0; nt < 4; nt++)
        acc[mt][nt] = __builtin_amdgcn_mfma_f32_16x16x32_f16(Ah[mt], Bh[nt], acc[mt][nt], 0, 0, 0);
  }
}

__device__ __forceinline__ void writeback_act64(
    f32x4 acc[4][4], const float* __restrict__ bias,
    f16* Xh, int w, int r16, int g) {
  #pragma unroll
  for (int nt = 0; nt < 4; nt++) {
    int nl = w * 64 + nt * 16 + r16;
    float bv = bias[nl];
    #pragma unroll
    for (int mt = 0; mt < 4; mt++)
      #pragma unroll
      for (int j = 0; j < 4; j++) {
        int m = mt * 16 + 4 * g + j;
        Xh[m * KP + nl] = (f16)lrelu(acc[mt][nt][j] + bv);
      }
  }
}

// ---------------- k_fused9: gather + MFMA MLP + maxpool + mlp2 + regress ----------------
template <int TRANS>
__global__ __launch_bounds__(256) void k_fused9(
    const float* __restrict__ xyz1, const float* __restrict__ xyz2,
    const float* __restrict__ points2, const unsigned short* __restrict__ p2t,
    const float* __restrict__ A1ws, const int* __restrict__ knn,
    const float* __restrict__ w1mlp,
    const f16* __restrict__ P1H, const f16* __restrict__ P2H,
    const f16* __restrict__ P3H,
    const float* __restrict__ b1, const float* __restrict__ b2,
    const float* __restrict__ b3,
    const float* __restrict__ W4T, const float* __restrict__ W5T,
    const float* __restrict__ regw, const float* __restrict__ regb,
    float* __restrict__ out) {
  int bid = blockIdx.x;
  // XCD swizzle: all 21 n1-blocks of a batch land on one XCD (2688 = 8*336)
  int xcd = bid & 7, slot = bid >> 3;
  int b = xcd * 16 + slot / 21;
  int n1 = slot % 21;
  int row = b * N1 + n1;

  int t = threadIdx.x;
  int lane = t & 63, w = t >> 6;
  int r16 = lane & 15, g = lane >> 4;

  __shared__ __align__(16) f16 Xhi[64 * KP];   // 34.3 KB -> 4 blocks/CU
  __shared__ float dirs[64][3];
  __shared__ int idxs[KNN];
  __shared__ float x1p[3];

  if (t < KNN) idxs[t] = knn[(size_t)row * KNN + t];
  if (t < 3) x1p[t] = xyz1[((size_t)b * 3 + t) * N1 + n1];
  __syncthreads();

  float a1v[4], wd0[4], wd1[4], wd2[4];
  #pragma unroll
  for (int nt = 0; nt < 4; nt++) {
    int n = w * 64 + nt * 16 + r16;
    a1v[nt] = A1ws[(size_t)row * 256 + n];
    wd0[nt] = w1mlp[(size_t)n * 387 + 384];
    wd1[nt] = w1mlp[(size_t)n * 387 + 385];
    wd2[nt] = w1mlp[(size_t)n * 387 + 386];
  }

  const float* x2b = xyz2 + (size_t)b * 3 * N2;
  if (t < 64) {
    int id = idxs[t];
    #pragma unroll
    for (int d = 0; d < 3; d++)
      dirs[t][d] = x2b[(size_t)d * N2 + id] - x1p[d];
  }
  // gather g2 [64 rows][256 ch]: 4 threads/row, 8 coalesced uint4 (16 B = 8 u16 ch) each
  if (TRANS) {
    int r = t >> 2, qq = t & 3;
    int id = idxs[r];
    const uint4* src = (const uint4*)(p2t + ((size_t)b * N2 + id) * CC + qq * 64);
    #pragma unroll
    for (int i = 0; i < 8; i++) {
      uint4 v = src[i];
      f16x8 val;
      __builtin_memcpy(&val, &v, 16);
      f16x4 lo4 = __builtin_shufflevector(val, val, 0, 1, 2, 3);
      f16x4 hi4 = __builtin_shufflevector(val, val, 4, 5, 6, 7);
      int cpos = r * KP + qq * 64 + i * 8;
      *(f16x4*)(Xhi + cpos) = lo4;
      *(f16x4*)(Xhi + cpos + 4) = hi4;
    }
  } else {
    int r = t >> 2, qq = t & 3;
    int id = idxs[r];
    const float* src = points2 + (size_t)b * CC * N2 + id;
    #pragma unroll 4
    for (int i = 0; i < 64; i++) {
      int c = qq * 64 + i;
      Xhi[r * KP + c] = (f16)src[(size_t)c * N2];
    }
  }
  __syncthreads();

  f32x4 acc[4][4];
  // ---- layer 1 (K=256 over g2), acc init = A1[n] + W1[n][384:387]·dir[m] ----
  #pragma unroll
  for (int mt = 0; mt < 4; mt++)
    #pragma unroll
    for (int nt = 0; nt < 4; nt++)
      #pragma unroll
      for (int j = 0; j < 4; j++) {
        int m = mt * 16 + 4 * g + j;
        acc[mt][nt][j] = a1v[nt] + wd0[nt] * dirs[m][0]
                                 + wd1[nt] * dirs[m][1]
                                 + wd2[nt] * dirs[m][2];
      }
  run_layer64(P1H, Xhi, w, lane, r16, g, acc);
  __syncthreads();
  writeback_act64(acc, b1, Xhi, w, r16, g);
  __syncthreads();

  // ---- layer 2 ----
  #pragma unroll
  for (int mt = 0; mt < 4; mt++)
    #pragma unroll
    for (int nt = 0; nt < 4; nt++) acc[mt][nt] = (f32x4){0.f, 0.f, 0.f, 0.f};
  run_layer64(P2H, Xhi, w, lane, r16, g, acc);
  __syncthreads();
  writeback_act64(acc, b2, Xhi, w, r16, g);
  __syncthreads();

  // ---- layer 3 + maxpool over all 64 rows (bias/lrelu deferred; commute with max) ----
  #pragma unroll
  for (int mt = 0; mt < 4; mt++)
    #pragma unroll
    for (int nt = 0; nt < 4; nt++) acc[mt][nt] = (f32x4){0.f, 0.f, 0.f, 0.f};
  run_layer64(P3H, Xhi, w, lane, r16, g, acc);

  float poolm[4];
  #pragma unroll
  for (int nt = 0; nt < 4; nt++) {
    float m = -FLT_MAX;
    #pragma unroll
    for (int mt = 0; mt < 4; mt++)
      #pragma unroll
      for (int j = 0; j < 4; j++) m = fmaxf(m, acc[mt][nt][j]);
    m = fmaxf(m, __shfl_xor(m, 16));
    m = fmaxf(m, __shfl_xor(m, 32));
    poolm[nt] = m;
  }
  __syncthreads();   // all waves done reading X -> reuse as float buffer

  // ---- tail: pooled -> mlp2 -> regress (fp32) ----
  float* fb = (float*)Xhi;   // [0:256) pooled, [256:512) z1, [512:768) z2
  if (g == 0) {
    #pragma unroll
    for (int nt = 0; nt < 4; nt++) {
      int n = w * 64 + nt * 16 + r16;
      fb[n] = lrelu(poolm[nt] + b3[n]);
    }
  }
  __syncthreads();
  {
    float a = 0.f;
    #pragma unroll 4
    for (int c = 0; c < 256; c++) a += W4T[(size_t)c * 256 + t] * fb[c];
    fb[256 + t] = lrelu(a);
  }
  __syncthreads();
  {
    float a = 0.f;
    #pragma unroll 4
    for (int c = 0; c < 256; c++) a += W5T[(size_t)c * 256 + t] * fb[256 + c];
    fb[512 + t] = lrelu(a);
  }
  __syncthreads();
  if (t < 192) {
    int o = t >> 6;
    float a = 0.f;
    #pragma unroll
    for (int i = 0; i < 4; i++) {
      int c = (t & 63) + 64 * i;
      a += regw[o * 256 + c] * fb[512 + c];
    }
    #pragma unroll
    for (int off = 32; off; off >>= 1) a += __shfl_xor(a, off);
    if ((t & 63) == 0) out[((size_t)b * 3 + o) * N1 + n1] = a + regb[o];
  }
}

extern "C" void kernel_launch(void* const* d_in, const int* in_sizes, int n_in,
                              void* d_out, int out_size, void* d_ws, size_t ws_size,
                              hipStream_t stream) {
  const float* xyz1    = (const float*)d_in[0];
  const float* xyz2    = (const float*)d_in[1];
  const float* points1 = (const float*)d_in[2];
  const float* points2 = (const float*)d_in[3];
  const float* bf_w1 = (const float*)d_in[4],  *bf_b1 = (const float*)d_in[5];
  const float* bf_g1 = (const float*)d_in[6],  *bf_e1 = (const float*)d_in[7];
  const float* bf_w2 = (const float*)d_in[8],  *bf_b2 = (const float*)d_in[9];
  const float* bf_g2 = (const float*)d_in[10], *bf_e2 = (const float*)d_in[11];
  const float* bf_w3 = (const float*)d_in[12], *bf_b3 = (const float*)d_in[13];
  const float* bf_g3 = (const float*)d_in[14], *bf_e3 = (const float*)d_in[15];
  const float* mlp_w1 = (const float*)d_in[16], *mlp_b1 = (const float*)d_in[17];
  const float* mlp_w2 = (const float*)d_in[18], *mlp_b2 = (const float*)d_in[19];
  const float* mlp_w3 = (const float*)d_in[20], *mlp_b3 = (const float*)d_in[21];
  const float* mlp2_w1 = (const float*)d_in[22], *mlp2_w2 = (const float*)d_in[23];
  const float* reg_w = (const float*)d_in[24], *reg_b = (const float*)d_in[25];

  float* ws  = (float*)d_ws;
  float* A1  = ws + OFF_A1;
  int*   knn = (int*)(ws + OFF_KNN);
  unsigned short* p2t = (unsigned short*)(ws + OFF_P2T);

  float* out = (float*)d_out;
  int rows = BB * N1;  // 2688

  size_t need_bytes = OFF_P2T * sizeof(float) + (size_t)BB * N2 * CC * sizeof(unsigned short);
  bool use_trans = (ws_size >= need_bytes);

  k_pack<<<1280, 256, 0, stream>>>(mlp_w1, mlp_w2, mlp_w3, mlp2_w1, mlp2_w2, ws);
  if (use_trans)
    k_t2<<<BB * 256, 256, 0, stream>>>(points2, p2t);
  k_biasfold<<<rows, 128, 0, stream>>>(points1,
      bf_w1, bf_b1, bf_g1, bf_e1,
      bf_w2, bf_b2, bf_g2, bf_e2,
      bf_w3, bf_b3, bf_g3, bf_e3, mlp_w1, A1);
  k_knn<<<rows, 256, 0, stream>>>(xyz1, xyz2, knn);
  if (use_trans)
    k_fused9<1><<<rows, 256, 0, stream>>>(xyz1, xyz2, points2, p2t, A1, knn, mlp_w1,
        (const f16*)(ws + OFF_P1H), (const f16*)(ws + OFF_P2H), (const f16*)(ws + OFF_P3H),
        mlp_b1, mlp_b2, mlp_b3,
        ws + OFF_W4T, ws + OFF_W5T, reg_w, reg_b, out);
  else
    k_fused9<0><<<rows, 256, 0, stream>>>(xyz1, xyz2, points2, p2t, A1, knn, mlp_w1,
        (const f16*)(ws + OFF_P1H), (const f16*)(ws + OFF_P2H), (const f16*)(ws + OFF_P3H),
        mlp_b1, mlp_b2, mlp_b3,
        ws + OFF_W4T, ws + OFF_W5T, reg_w, reg_b, out);
}

// Round 11
// 656.419 us; speedup vs baseline: 1.7630x; 1.0506x over previous
//
#include <hip/hip_runtime.h>
#include <float.h>

#define BB 128
#define N1 21
#define N2 4096
#define CC 256   // C (points2 channels)
#define LCH 256  // LC
#define HH 128   // H
#define KNN 64
#define KP 268   // LDS X row stride in f16 (256 + pad; 8B-aligned rows, bank stride 6)

typedef _Float16 f16;
typedef f16 f16x4 __attribute__((ext_vector_type(4)));
typedef f16 f16x8 __attribute__((ext_vector_type(8)));
typedef float f32x4 __attribute__((ext_vector_type(4)));

// ---- workspace layout (float units) ----
static const size_t OFF_A1   = 0;                                   // [2688][256] f32
static const size_t OFF_KNN  = OFF_A1 + (size_t)BB * N1 * 256;      // [2688][64] int
static const size_t OFF_W4T  = OFF_KNN + (size_t)BB * N1 * KNN;     // [256][256] f32
static const size_t OFF_W5T  = OFF_W4T + 65536;
static const size_t OFF_P1H  = OFF_W5T + 65536;                     // each pack: 65536 f16 = 32768 f32
static const size_t OFF_P2H  = OFF_P1H + 32768;
static const size_t OFF_P3H  = OFF_P2H + 32768;
static const size_t OFF_USED = OFF_P3H + 32768;                     // [B][4096] u8 = 512 KB
static const size_t OFF_P2T  = OFF_USED + 131072;                   // [B][N2][C] u16 (f16) = 256 MB

__device__ __forceinline__ float lrelu(float x) { return x > 0.f ? x : 0.1f * x; }
__device__ __forceinline__ unsigned short bits16(f16 h) { unsigned short r; __builtin_memcpy(&r, &h, 2); return r; }

// fragment k-mapping kappa(lane,j) = 4*(lane>>4) + (j&3) + 16*(j>>2), used for BOTH
// A and B packing -> k-permutation cancels in the dot product.
// Precision: single-f16 operands; r10 measured absmax 1.95e-3 vs 6.17e-3 threshold.

// ---------------- kernel 0: weight pack (f16) ----------------
__device__ __forceinline__ void pack_one(int e, const float* __restrict__ w, int stride, int koff,
                                         f16* __restrict__ hi) {
  int j = e & 7, lane = (e >> 3) & 63, ntg = (e >> 9) & 15, ks = e >> 13;
  int n = ntg * 16 + (lane & 15);
  int k = ks * 32 + 4 * (lane >> 4) + (j & 3) + 16 * (j >> 2);
  hi[e] = (f16)w[(size_t)n * stride + koff + k];
}

__global__ __launch_bounds__(256) void k_pack(
    const float* __restrict__ w1, const float* __restrict__ w2,
    const float* __restrict__ w3, const float* __restrict__ w4,
    const float* __restrict__ w5, float* __restrict__ ws) {
  int t = blockIdx.x * 256 + threadIdx.x;
  if (t < 131072) {   // W4T / W5T fp32 transpose
    int m = t >> 16, v = t & 65535;
    int c = v >> 8, o = v & 255;
    const float* src = m ? w5 : w4;
    float* dst = ws + (m ? OFF_W5T : OFF_W4T);
    dst[v] = src[o * 256 + c];
    return;
  }
  int u = t - 131072;
  if (u < 65536) { pack_one(u, w1, 387, 128, (f16*)(ws + OFF_P1H)); return; }
  u -= 65536;
  if (u < 65536) { pack_one(u, w2, 256, 0, (f16*)(ws + OFF_P2H)); return; }
  u -= 65536;
  if (u < 65536) { pack_one(u, w3, 256, 0, (f16*)(ws + OFF_P3H)); return; }
}

// ---------------- kernel 0a: zero the used bitmap (must precede k_knn) ----------------
__global__ __launch_bounds__(256) void k_zero(unsigned int* __restrict__ used32) {
  used32[blockIdx.x * 256 + threadIdx.x] = 0;
}

// ---------------- kernel 1: biasfold -> A1 (p1-part of mlp layer 1 folded in) ----------------
__global__ __launch_bounds__(128) void k_biasfold(
    const float* __restrict__ points1,
    const float* __restrict__ w1, const float* __restrict__ bb1,
    const float* __restrict__ g1, const float* __restrict__ be1,
    const float* __restrict__ w2, const float* __restrict__ bb2,
    const float* __restrict__ g2, const float* __restrict__ be2,
    const float* __restrict__ w3, const float* __restrict__ bb3,
    const float* __restrict__ g3, const float* __restrict__ be3,
    const float* __restrict__ w1mlp,
    float* __restrict__ A1out) {
  int blk = blockIdx.x;
  int b = blk / N1, n = blk % N1;
  int t = threadIdx.x;
  __shared__ float x0[LCH], x1s[HH], x2s[HH], x3s[HH];
  const float bnS = 1.0f / sqrtf(1.0f + 1e-5f);

  x0[t]       = points1[((size_t)b * LCH + t) * N1 + n];
  x0[t + 128] = points1[((size_t)b * LCH + t + 128) * N1 + n];
  __syncthreads();
  {
    float acc = 0.f;
    const float* wr = w1 + (size_t)t * LCH;
    #pragma unroll 4
    for (int c = 0; c < LCH; c++) acc += wr[c] * x0[c];
    acc += bb1[t * N1 + n];
    acc = acc * (g1[t] * bnS) + be1[t];
    x1s[t] = lrelu(acc);
  }
  __syncthreads();
  {
    float acc = 0.f;
    const float* wr = w2 + (size_t)t * HH;
    #pragma unroll 4
    for (int c = 0; c < HH; c++) acc += wr[c] * x1s[c];
    acc += bb2[t * N1 + n];
    acc = acc * (g2[t] * bnS) + be2[t];
    x2s[t] = lrelu(acc);
  }
  __syncthreads();
  {
    float acc = 0.f;
    const float* wr = w3 + (size_t)t * HH;
    #pragma unroll 4
    for (int c = 0; c < HH; c++) acc += wr[c] * x2s[c];
    acc += bb3[t * N1 + n];
    acc = acc * (g3[t] * bnS) + be3[t];
    x3s[t] = lrelu(acc);
  }
  __syncthreads();
  #pragma unroll
  for (int rep = 0; rep < 2; rep++) {
    int o = t + rep * 128;
    const float* wr = w1mlp + (size_t)o * 387;
    float acc = 0.f;
    #pragma unroll 4
    for (int c = 0; c < HH; c++) acc += wr[c] * x3s[c];
    A1out[(size_t)blk * 256 + o] = acc;
  }
}

// ---------------- kernel 2: kNN, register-resident dists, 1 barrier/iter ----------------
// wvv/wii double-buffered by iteration parity: writers target slot (it&1), readers read the
// same slot after the barrier; a wave at most 1 iter ahead writes the OTHER slot -> safe.
// Also marks used[b][n2] for t2's predicated write (same-value races benign).
__global__ __launch_bounds__(256) void k_knn(
    const float* __restrict__ xyz1, const float* __restrict__ xyz2,
    int* __restrict__ knn, unsigned char* __restrict__ used) {
  int blk = blockIdx.x;
  int b = blk / N1, n = blk % N1;
  int t = threadIdx.x;
  __shared__ float wvv[2][4];
  __shared__ int wii[2][4];

  float ax = xyz1[((size_t)b * 3 + 0) * N1 + n];
  float ay = xyz1[((size_t)b * 3 + 1) * N1 + n];
  float az = xyz1[((size_t)b * 3 + 2) * N1 + n];
  float xx1 = ax * ax + ay * ay + az * az;
  const float* X = xyz2 + (size_t)b * 3 * N2;

  float dl[16];
  #pragma unroll
  for (int i = 0; i < 16; i++) {
    int j = t + i * 256;
    float px = X[j], py = X[N2 + j], pz = X[2 * N2 + j];
    float xx2 = px * px + py * py + pz * pz;
    float dot = ax * px + ay * py + az * pz;
    dl[i] = (xx1 + xx2) - 2.0f * dot;
  }

  int* out = knn + (size_t)blk * KNN;
  unsigned char* ub = used + (size_t)b * N2;
  for (int it = 0; it < KNN; it++) {
    float best = dl[0]; int bs = 0;
    #pragma unroll
    for (int i = 1; i < 16; i++)
      if (dl[i] < best) { best = dl[i]; bs = i; }
    int bi = t + bs * 256;
    #pragma unroll
    for (int off = 32; off; off >>= 1) {
      float ov = __shfl_down(best, off);
      int oi = __shfl_down(bi, off);
      if (ov < best || (ov == best && oi < bi)) { best = ov; bi = oi; }
    }
    int w = t >> 6;
    int sl = it & 1;
    if ((t & 63) == 0) { wvv[sl][w] = best; wii[sl][w] = bi; }
    __syncthreads();
    float bv = wvv[sl][0]; int bj = wii[sl][0];
    #pragma unroll
    for (int p = 1; p < 4; p++)
      if (wvv[sl][p] < bv || (wvv[sl][p] == bv && wii[sl][p] < bj)) { bv = wvv[sl][p]; bj = wii[sl][p]; }
    if (t == 0) { out[it] = bj; ub[bj] = 1; }
    if ((bj & 255) == t) {
      int slot = bj >> 8;
      #pragma unroll
      for (int i = 0; i < 16; i++)
        if (i == slot) dl[i] = FLT_MAX;
    }
    // no trailing barrier: next iter writes the other wvv slot
  }
}

// ---------------- kernel 0b: points2 -> P2T, write predicated on used ----------------
// Runs AFTER k_knn. Store row index is wave-uniform -> unused rows skip the full
// 128 B store (s_cbranch). ~32% of points are used -> write 256 MB -> ~84 MB.
__global__ __launch_bounds__(256) void k_t2(
    const float* __restrict__ points2, unsigned short* __restrict__ p2t,
    const unsigned char* __restrict__ used) {
  __shared__ unsigned short tile[64][66];
  int bid = blockIdx.x;
  int b = bid >> 8;
  int rem = bid & 255;
  int n0 = (rem >> 2) << 6;   // 64 n2-block
  int c0 = (rem & 3) << 6;    // 64 c-block
  int t = threadIdx.x;
  int tl = t & 63, tg = t >> 6;

  const float* src = points2 + ((size_t)b * CC) * N2;
  float v[16];
  #pragma unroll
  for (int i = 0; i < 16; i++)
    v[i] = src[(size_t)(c0 + tg * 16 + i) * N2 + n0 + tl];   // 16 loads in flight
  #pragma unroll
  for (int i = 0; i < 16; i++)
    tile[tg * 16 + i][tl] = bits16((f16)v[i]);

  // 16 contiguous used-bytes for this wave's output rows (one uint4)
  uint4 ubv = *(const uint4*)(used + (size_t)b * N2 + n0 + tg * 16);
  const unsigned char* ubb = (const unsigned char*)&ubv;

  __syncthreads();
  unsigned short* dst = p2t + ((size_t)b * N2) * CC;
  unsigned short o[16];
  #pragma unroll
  for (int i = 0; i < 16; i++) o[i] = tile[tl][tg * 16 + i];
  #pragma unroll
  for (int i = 0; i < 16; i++)
    if (ubb[i])
      dst[(size_t)(n0 + tg * 16 + i) * CC + c0 + tl] = o[i];
}

// ---------------- MFMA layer: M=64 x N=64 per wave, single f16, K=256 ----------------
// ks loop MUST stay rolled (#pragma unroll 1): full unroll hoists all k-steps' B loads
// -> >256 live VGPRs -> scratch spill (r3/r4/r5: 2.25/2.13/1.24 GB WRITE_SIZE).
__device__ __forceinline__ void run_layer64(
    const f16* __restrict__ BH, const f16* Xh,
    int w, int lane, int r16, int g, f32x4 acc[4][4]) {
  #pragma unroll 1
  for (int ks = 0; ks < 8; ks++) {
    f16x8 Bh[4];
    #pragma unroll
    for (int nt = 0; nt < 4; nt++) {
      size_t fi = ((size_t)((ks * 16 + w * 4 + nt) * 64 + lane)) * 8;
      Bh[nt] = *(const f16x8*)(BH + fi);
    }
    int k0 = ks * 32 + 4 * g;
    f16x8 Ah[4];
    #pragma unroll
    for (int mt = 0; mt < 4; mt++) {
      int base = (mt * 16 + r16) * KP + k0;
      f16x4 h0 = *(const f16x4*)(Xh + base);
      f16x4 h1 = *(const f16x4*)(Xh + base + 16);
      Ah[mt] = __builtin_shufflevector(h0, h1, 0, 1, 2, 3, 4, 5, 6, 7);
    }
    #pragma unroll
    for (int mt = 0; mt < 4; mt++)
      #pragma unroll
      for (int nt = 0; nt < 4; nt++)
        acc[mt][nt] = __builtin_amdgcn_mfma_f32_16x16x32_f16(Ah[mt], Bh[nt], acc[mt][nt], 0, 0, 0);
  }
}

__device__ __forceinline__ void writeback_act64(
    f32x4 acc[4][4], const float* __restrict__ bias,
    f16* Xh, int w, int r16, int g) {
  #pragma unroll
  for (int nt = 0; nt < 4; nt++) {
    int nl = w * 64 + nt * 16 + r16;
    float bv = bias[nl];
    #pragma unroll
    for (int mt = 0; mt < 4; mt++)
      #pragma unroll
      for (int j = 0; j < 4; j++) {
        int m = mt * 16 + 4 * g + j;
        Xh[m * KP + nl] = (f16)lrelu(acc[mt][nt][j] + bv);
      }
  }
}

// ---------------- k_fused9: gather + MFMA MLP + maxpool + mlp2 + regress ----------------
template <int TRANS>
__global__ __launch_bounds__(256) void k_fused9(
    const float* __restrict__ xyz1, const float* __restrict__ xyz2,
    const float* __restrict__ points2, const unsigned short* __restrict__ p2t,
    const float* __restrict__ A1ws, const int* __restrict__ knn,
    const float* __restrict__ w1mlp,
    const f16* __restrict__ P1H, const f16* __restrict__ P2H,
    const f16* __restrict__ P3H,
    const float* __restrict__ b1, const float* __restrict__ b2,
    const float* __restrict__ b3,
    const float* __restrict__ W4T, const float* __restrict__ W5T,
    const float* __restrict__ regw, const float* __restrict__ regb,
    float* __restrict__ out) {
  int bid = blockIdx.x;
  // XCD swizzle: all 21 n1-blocks of a batch land on one XCD (2688 = 8*336)
  int xcd = bid & 7, slot = bid >> 3;
  int b = xcd * 16 + slot / 21;
  int n1 = slot % 21;
  int row = b * N1 + n1;

  int t = threadIdx.x;
  int lane = t & 63, w = t >> 6;
  int r16 = lane & 15, g = lane >> 4;

  __shared__ __align__(16) f16 Xhi[64 * KP];   // 34.3 KB -> 4 blocks/CU
  __shared__ float dirs[64][3];
  __shared__ int idxs[KNN];
  __shared__ float x1p[3];

  if (t < KNN) idxs[t] = knn[(size_t)row * KNN + t];
  if (t < 3) x1p[t] = xyz1[((size_t)b * 3 + t) * N1 + n1];
  __syncthreads();

  // ---- gather FIRST (longest-latency loads issue before constants) ----
  if (TRANS) {
    int r = t >> 2, qq = t & 3;
    int id = idxs[r];
    const uint4* src = (const uint4*)(p2t + ((size_t)b * N2 + id) * CC + qq * 64);
    #pragma unroll
    for (int i = 0; i < 8; i++) {
      uint4 v = src[i];
      f16x8 val;
      __builtin_memcpy(&val, &v, 16);
      f16x4 lo4 = __builtin_shufflevector(val, val, 0, 1, 2, 3);
      f16x4 hi4 = __builtin_shufflevector(val, val, 4, 5, 6, 7);
      int cpos = r * KP + qq * 64 + i * 8;
      *(f16x4*)(Xhi + cpos) = lo4;
      *(f16x4*)(Xhi + cpos + 4) = hi4;
    }
  } else {
    int r = t >> 2, qq = t & 3;
    int id = idxs[r];
    const float* src = points2 + (size_t)b * CC * N2 + id;
    #pragma unroll 4
    for (int i = 0; i < 64; i++) {
      int c = qq * 64 + i;
      Xhi[r * KP + c] = (f16)src[(size_t)c * N2];
    }
  }
  const float* x2b = xyz2 + (size_t)b * 3 * N2;
  if (t < 64) {
    int id = idxs[t];
    #pragma unroll
    for (int d = 0; d < 3; d++)
      dirs[t][d] = x2b[(size_t)d * N2 + id] - x1p[d];
  }

  // per-lane constants load after the gather is in flight
  float a1v[4], wd0[4], wd1[4], wd2[4];
  #pragma unroll
  for (int nt = 0; nt < 4; nt++) {
    int n = w * 64 + nt * 16 + r16;
    a1v[nt] = A1ws[(size_t)row * 256 + n];
    wd0[nt] = w1mlp[(size_t)n * 387 + 384];
    wd1[nt] = w1mlp[(size_t)n * 387 + 385];
    wd2[nt] = w1mlp[(size_t)n * 387 + 386];
  }
  __syncthreads();

  f32x4 acc[4][4];
  // ---- layer 1 (K=256 over g2), acc init = A1[n] + W1[n][384:387]·dir[m] ----
  #pragma unroll
  for (int mt = 0; mt < 4; mt++)
    #pragma unroll
    for (int nt = 0; nt < 4; nt++)
      #pragma unroll
      for (int j = 0; j < 4; j++) {
        int m = mt * 16 + 4 * g + j;
        acc[mt][nt][j] = a1v[nt] + wd0[nt] * dirs[m][0]
                                 + wd1[nt] * dirs[m][1]
                                 + wd2[nt] * dirs[m][2];
      }
  run_layer64(P1H, Xhi, w, lane, r16, g, acc);
  __syncthreads();
  writeback_act64(acc, b1, Xhi, w, r16, g);
  __syncthreads();

  // ---- layer 2 ----
  #pragma unroll
  for (int mt = 0; mt < 4; mt++)
    #pragma unroll
    for (int nt = 0; nt < 4; nt++) acc[mt][nt] = (f32x4){0.f, 0.f, 0.f, 0.f};
  run_layer64(P2H, Xhi, w, lane, r16, g, acc);
  __syncthreads();
  writeback_act64(acc, b2, Xhi, w, r16, g);
  __syncthreads();

  // ---- layer 3 + maxpool over all 64 rows (bias/lrelu deferred; commute with max) ----
  #pragma unroll
  for (int mt = 0; mt < 4; mt++)
    #pragma unroll
    for (int nt = 0; nt < 4; nt++) acc[mt][nt] = (f32x4){0.f, 0.f, 0.f, 0.f};
  run_layer64(P3H, Xhi, w, lane, r16, g, acc);

  float poolm[4];
  #pragma unroll
  for (int nt = 0; nt < 4; nt++) {
    float m = -FLT_MAX;
    #pragma unroll
    for (int mt = 0; mt < 4; mt++)
      #pragma unroll
      for (int j = 0; j < 4; j++) m = fmaxf(m, acc[mt][nt][j]);
    m = fmaxf(m, __shfl_xor(m, 16));
    m = fmaxf(m, __shfl_xor(m, 32));
    poolm[nt] = m;
  }
  __syncthreads();   // all waves done reading X -> reuse as float buffer

  // ---- tail: pooled -> mlp2 -> regress (fp32) ----
  float* fb = (float*)Xhi;   // [0:256) pooled, [256:512) z1, [512:768) z2
  if (g == 0) {
    #pragma unroll
    for (int nt = 0; nt < 4; nt++) {
      int n = w * 64 + nt * 16 + r16;
      fb[n] = lrelu(poolm[nt] + b3[n]);
    }
  }
  __syncthreads();
  {
    float a = 0.f;
    #pragma unroll 4
    for (int c = 0; c < 256; c++) a += W4T[(size_t)c * 256 + t] * fb[c];
    fb[256 + t] = lrelu(a);
  }
  __syncthreads();
  {
    float a = 0.f;
    #pragma unroll 4
    for (int c = 0; c < 256; c++) a += W5T[(size_t)c * 256 + t] * fb[256 + c];
    fb[512 + t] = lrelu(a);
  }
  __syncthreads();
  if (t < 192) {
    int o = t >> 6;
    float a = 0.f;
    #pragma unroll
    for (int i = 0; i < 4; i++) {
      int c = (t & 63) + 64 * i;
      a += regw[o * 256 + c] * fb[512 + c];
    }
    #pragma unroll
    for (int off = 32; off; off >>= 1) a += __shfl_xor(a, off);
    if ((t & 63) == 0) out[((size_t)b * 3 + o) * N1 + n1] = a + regb[o];
  }
}

extern "C" void kernel_launch(void* const* d_in, const int* in_sizes, int n_in,
                              void* d_out, int out_size, void* d_ws, size_t ws_size,
                              hipStream_t stream) {
  const float* xyz1    = (const float*)d_in[0];
  const float* xyz2    = (const float*)d_in[1];
  const float* points1 = (const float*)d_in[2];
  const float* points2 = (const float*)d_in[3];
  const float* bf_w1 = (const float*)d_in[4],  *bf_b1 = (const float*)d_in[5];
  const float* bf_g1 = (const float*)d_in[6],  *bf_e1 = (const float*)d_in[7];
  const float* bf_w2 = (const float*)d_in[8],  *bf_b2 = (const float*)d_in[9];
  const float* bf_g2 = (const float*)d_in[10], *bf_e2 = (const float*)d_in[11];
  const float* bf_w3 = (const float*)d_in[12], *bf_b3 = (const float*)d_in[13];
  const float* bf_g3 = (const float*)d_in[14], *bf_e3 = (const float*)d_in[15];
  const float* mlp_w1 = (const float*)d_in[16], *mlp_b1 = (const float*)d_in[17];
  const float* mlp_w2 = (const float*)d_in[18], *mlp_b2 = (const float*)d_in[19];
  const float* mlp_w3 = (const float*)d_in[20], *mlp_b3 = (const float*)d_in[21];
  const float* mlp2_w1 = (const float*)d_in[22], *mlp2_w2 = (const float*)d_in[23];
  const float* reg_w = (const float*)d_in[24], *reg_b = (const float*)d_in[25];

  float* ws  = (float*)d_ws;
  float* A1  = ws + OFF_A1;
  int*   knn = (int*)(ws + OFF_KNN);
  unsigned char* used = (unsigned char*)(ws + OFF_USED);
  unsigned short* p2t = (unsigned short*)(ws + OFF_P2T);

  float* out = (float*)d_out;
  int rows = BB * N1;  // 2688

  size_t need_bytes = OFF_P2T * sizeof(float) + (size_t)BB * N2 * CC * sizeof(unsigned short);
  bool use_trans = (ws_size >= need_bytes);

  k_pack<<<1280, 256, 0, stream>>>(mlp_w1, mlp_w2, mlp_w3, mlp2_w1, mlp2_w2, ws);
  k_biasfold<<<rows, 128, 0, stream>>>(points1,
      bf_w1, bf_b1, bf_g1, bf_e1,
      bf_w2, bf_b2, bf_g2, bf_e2,
      bf_w3, bf_b3, bf_g3, bf_e3, mlp_w1, A1);
  k_zero<<<512, 256, 0, stream>>>((unsigned int*)used);
  k_knn<<<rows, 256, 0, stream>>>(xyz1, xyz2, knn, used);
  if (use_trans) {
    k_t2<<<BB * 256, 256, 0, stream>>>(points2, p2t, used);
    k_fused9<1><<<rows, 256, 0, stream>>>(xyz1, xyz2, points2, p2t, A1, knn, mlp_w1,
        (const f16*)(ws + OFF_P1H), (const f16*)(ws + OFF_P2H), (const f16*)(ws + OFF_P3H),
        mlp_b1, mlp_b2, mlp_b3,
        ws + OFF_W4T, ws + OFF_W5T, reg_w, reg_b, out);
  } else {
    k_fused9<0><<<rows, 256, 0, stream>>>(xyz1, xyz2, points2, p2t, A1, knn, mlp_w1,
        (const f16*)(ws + OFF_P1H), (const f16*)(ws + OFF_P2H), (const f16*)(ws + OFF_P3H),
        mlp_b1, mlp_b2, mlp_b3,
        ws + OFF_W4T, ws + OFF_W5T, reg_w, reg_b, out);
  }
}